// Round 8
// baseline (1633.400 us; speedup 1.0000x reference)
//
#include <hip/hip_runtime.h>

#define N_MI 100000
#define N_DI 50000
#define MI_P 100352   // multiple of 256
#define DI_P 50176    // multiple of 256
#define MIB  ((N_MI + 1023) / 1024)   // 98 scan blocks
#define DIB  ((N_DI + 1023) / 1024)   // 49

typedef _Float16 half8  __attribute__((ext_vector_type(8)));
typedef _Float16 half4  __attribute__((ext_vector_type(4)));
typedef float    floatx4 __attribute__((ext_vector_type(4)));

// ---------------------------------------------------------------------------
// CSR build: count
// ---------------------------------------------------------------------------
__global__ void count_kernel(const int* __restrict__ src, const int* __restrict__ dst,
                             int* deg_mi, int* deg_di, int E) {
    int i = blockIdx.x * blockDim.x + threadIdx.x;
    if (i < E) {
        atomicAdd(&deg_mi[src[i]], 1);
        atomicAdd(&deg_di[dst[i]], 1);
    }
}

// ---------------------------------------------------------------------------
// Parallel exclusive scan, 3 passes. blockIdx.y: 0=di, 1=mi.
// ---------------------------------------------------------------------------
__global__ __launch_bounds__(256) void scanA_kernel(const int* __restrict__ deg_di,
                                                    const int* __restrict__ deg_mi,
                                                    int* __restrict__ bs_di,
                                                    int* __restrict__ bs_mi) {
    const int* deg; int* bs; int n;
    if (blockIdx.y == 0) { deg = deg_di; bs = bs_di; n = N_DI; }
    else                 { deg = deg_mi; bs = bs_mi; n = N_MI; }
    if ((int)blockIdx.x * 1024 >= n) return;
    __shared__ int ws[4];
    int tid = threadIdx.x, lane = tid & 63, w = tid >> 6;
    long base = (long)blockIdx.x * 1024 + tid * 4;
    int x0 = 0, x1 = 0, x2 = 0, x3 = 0;
    if (base + 4 <= n) {
        int4 v = *(const int4*)(deg + base);
        x0 = v.x; x1 = v.y; x2 = v.z; x3 = v.w;
    } else {
        if (base < n)     x0 = deg[base];
        if (base + 1 < n) x1 = deg[base + 1];
        if (base + 2 < n) x2 = deg[base + 2];
        if (base + 3 < n) x3 = deg[base + 3];
    }
    int s = x0 + x1 + x2 + x3;
    #pragma unroll
    for (int off = 32; off >= 1; off >>= 1) s += __shfl_down(s, off, 64);
    if (lane == 0) ws[w] = s;
    __syncthreads();
    if (tid == 0) bs[blockIdx.x] = ws[0] + ws[1] + ws[2] + ws[3];
}

__global__ void scanB_kernel(int* bs_di, int* bs_mi, int* row_di, int* row_mi) {
    int* bs; int nb; int* rown;
    if (blockIdx.x == 0) { bs = bs_di; nb = DIB; rown = row_di + N_DI; }
    else                 { bs = bs_mi; nb = MIB; rown = row_mi + N_MI; }
    int lane = threadIdx.x;   // 64 threads
    int carry = 0;
    for (int c = 0; c < nb; c += 64) {
        int i = c + lane;
        int v = (i < nb) ? bs[i] : 0;
        int x = v;
        #pragma unroll
        for (int off = 1; off < 64; off <<= 1) {
            int y = __shfl_up(x, off, 64);
            if (lane >= off) x += y;
        }
        if (i < nb) bs[i] = carry + x - v;   // exclusive, in place
        carry += __shfl(x, 63, 64);
    }
    if (lane == 0) *rown = carry;
}

__global__ __launch_bounds__(256) void scanC_kernel(const int* __restrict__ deg_di,
                                                    const int* __restrict__ deg_mi,
                                                    const int* __restrict__ bs_di,
                                                    const int* __restrict__ bs_mi,
                                                    int* __restrict__ row_di,
                                                    int* __restrict__ row_mi) {
    const int* deg; const int* bs; int* row; int n;
    if (blockIdx.y == 0) { deg = deg_di; bs = bs_di; row = row_di; n = N_DI; }
    else                 { deg = deg_mi; bs = bs_mi; row = row_mi; n = N_MI; }
    if ((int)blockIdx.x * 1024 >= n) return;
    __shared__ int ws[4];
    int tid = threadIdx.x, lane = tid & 63, w = tid >> 6;
    long base = (long)blockIdx.x * 1024 + tid * 4;
    int x0 = 0, x1 = 0, x2 = 0, x3 = 0;
    if (base + 4 <= n) {
        int4 v = *(const int4*)(deg + base);
        x0 = v.x; x1 = v.y; x2 = v.z; x3 = v.w;
    } else {
        if (base < n)     x0 = deg[base];
        if (base + 1 < n) x1 = deg[base + 1];
        if (base + 2 < n) x2 = deg[base + 2];
        if (base + 3 < n) x3 = deg[base + 3];
    }
    int ts = x0 + x1 + x2 + x3;
    int x = ts;
    #pragma unroll
    for (int off = 1; off < 64; off <<= 1) {
        int y = __shfl_up(x, off, 64);
        if (lane >= off) x += y;
    }
    if (lane == 63) ws[w] = x;
    __syncthreads();
    int woff = bs[blockIdx.x];
    for (int i = 0; i < w; ++i) woff += ws[i];
    int ex = woff + x - ts;
    if (base < n)     row[base]     = ex;
    if (base + 1 < n) row[base + 1] = ex + x0;
    if (base + 2 < n) row[base + 2] = ex + x0 + x1;
    if (base + 3 < n) row[base + 3] = ex + x0 + x1 + x2;
}

__global__ void fill_kernel(const int* __restrict__ src, const int* __restrict__ dst,
                            const int* __restrict__ row_mi, const int* __restrict__ row_di,
                            int* cur_mi, int* cur_di, int* csr_mi, int* csr_di, int E) {
    int i = blockIdx.x * blockDim.x + threadIdx.x;
    if (i >= E) return;
    int s = src[i], d = dst[i];
    int p = atomicAdd(&cur_di[d], 1);
    csr_di[row_di[d] + p] = s;
    int q = atomicAdd(&cur_mi[s], 1);
    csr_mi[row_mi[s] + q] = d;
}

// ---------------------------------------------------------------------------
// Fragment-linear layout for [Mpad x K] (K = KI*32):
//   chunk c (8 halves): lane=c&63 (lr=lane&15 row-in-16, q=lane>>4 ksub),
//   i=(c>>6)&3, k=(c>>8)%KI, mt=(c>>8)/KI.
//   element: row = mt*64+i*16+lr, col = k*32+q*8+e.
//   offset(row m, col n) = (((m>>6)*KI + (n>>5))*4 + ((m>>4)&3))*512
//                          + ((m&15) + 16*((n>>3)&3))*8 + (n&7)
// ---------------------------------------------------------------------------

// fp32 W [N x K] -> frag-linear fp16
struct CvtW {
    const float* s[14];
    _Float16* d[14];
    int K[14];
    int KI[14];
    int nch[14];
};

__global__ void cvtw_kernel(CvtW a) {
    int arr = blockIdx.y;
    int c = blockIdx.x * blockDim.x + threadIdx.x;
    if (c >= a.nch[arr]) return;
    int K = a.K[arr], KI = a.KI[arr];
    int lane = c & 63;
    int j = (c >> 6) & 3;
    int rest = c >> 8;
    int k = rest % KI;
    int p = rest / KI;
    int row = p * 64 + j * 16 + (lane & 15);
    int kcol = k * 32 + (lane >> 4) * 8;
    const float* s = a.s[arr] + (long)row * K + kcol;
    float4 u = *(const float4*)s;
    float4 v = *(const float4*)(s + 4);
    half8 h = {(_Float16)u.x, (_Float16)u.y, (_Float16)u.z, (_Float16)u.w,
               (_Float16)v.x, (_Float16)v.y, (_Float16)v.z, (_Float16)v.w};
    *(half8*)(a.d[arr] + (long)c * 8) = h;
}

// fp32 row-major [M x K] -> frag-linear fp16 via padded-LDS transpose
template<int K>
__global__ __launch_bounds__(256) void cvt_frag(const float* __restrict__ in,
                                                _Float16* __restrict__ out, int M) {
    constexpr int KI = K / 32;
    constexpr int CPR = K / 8;
    __shared__ _Float16 lds[64 * (K + 8)];
    const int tile = blockIdx.x;
    const int tid = threadIdx.x;
    #pragma unroll
    for (int it = 0; it < KI; ++it) {
        int c = tid + it * 256;
        int r = c / CPR, col = c % CPR;
        int row = tile * 64 + r;
        if (row >= M) row = M - 1;
        const float* g = in + (long)row * K + col * 8;
        float4 u = *(const float4*)g;
        float4 v = *(const float4*)(g + 4);
        half8 h = {(_Float16)u.x, (_Float16)u.y, (_Float16)u.z, (_Float16)u.w,
                   (_Float16)v.x, (_Float16)v.y, (_Float16)v.z, (_Float16)v.w};
        *(half8*)&lds[r * (K + 8) + col * 8] = h;
    }
    __syncthreads();
    #pragma unroll
    for (int it = 0; it < KI; ++it) {
        int c = tid + it * 256;
        int lane = c & 63, i = (c >> 6) & 3, k = c >> 8;
        half8 h = *(const half8*)&lds[(i * 16 + (lane & 15)) * (K + 8) + k * 32 + (lane >> 4) * 8];
        *(half8*)(out + ((long)tile * 8 * K + c) * 8) = h;
    }
}

// ---------------------------------------------------------------------------
// Mean aggregation: one node per wave; frag-linear in AND out.
// ---------------------------------------------------------------------------
template<int DIN>
__global__ __launch_bounds__(256) void agg2_kernel(const _Float16* __restrict__ hf,
                                                   const int* __restrict__ row,
                                                   const int* __restrict__ csr,
                                                   _Float16* __restrict__ outf, int n) {
    constexpr int LPR = DIN / 8;
    constexpr int GR  = 64 / LPR;
    constexpr int KI  = DIN / 32;
    int node = blockIdx.x * 4 + (threadIdx.x >> 6);
    if (node >= n) return;
    int lane = threadIdx.x & 63;
    int g = lane / LPR, c = lane % LPR;
    int k = c >> 2, qc = c & 3;
    long coff = ((long)k * 4) * 512 + 16 * qc * 8;   // col-part of frag offset
    int beg = row[node], end = row[node + 1];
    float acc[8] = {};
    #pragma unroll 2
    for (int j = beg + g; j < end; j += GR) {
        int nb = csr[j];
        long off = (((long)(nb >> 6) * KI) * 4 + ((nb >> 4) & 3)) * 512 + (nb & 15) * 8 + coff;
        half8 v = *(const half8*)(hf + off);
        #pragma unroll
        for (int e = 0; e < 8; ++e) acc[e] += (float)v[e];
    }
    float inv = 1.f / (float)max(end - beg, 1);
    half8 o;
    #pragma unroll
    for (int e = 0; e < 8; ++e) {
        float s = acc[e];
        s += __shfl_down(s, 32);
        if (GR == 4) s += __shfl_down(s, 16);
        o[e] = (_Float16)(s * inv);
    }
    if (g == 0) {
        long off = (((long)(node >> 6) * KI) * 4 + ((node >> 4) & 3)) * 512 + (node & 15) * 8 + coff;
        *(half8*)(outf + off) = o;
    }
}

// ---------------------------------------------------------------------------
// Fragment-linear fp16 MFMA GEMM: contiguous 1-KB wave-stream loads, no LDS.
// Writes OUTPUT IN FRAG-LINEAR layout (scattered half stores, full coverage).
// C = act(A1@W1^T [+ A2@W2^T] + bias [+ Cadd_f32 row-major]); KIO = N/32.
// ---------------------------------------------------------------------------
template<int KI, int KIO, bool DUAL>
__global__ __launch_bounds__(256, 3) void hgemm_f(
    const _Float16* __restrict__ A1f, const _Float16* __restrict__ W1f,
    const _Float16* __restrict__ A2f, const _Float16* __restrict__ W2f,
    const float* __restrict__ bias, const float* __restrict__ Cadd,
    _Float16* __restrict__ Cf, int M, int N, int relu)
{
    const int wave = threadIdx.x >> 6, lane = threadIdx.x & 63;
    const int quad = lane >> 4, lr = lane & 15;
    const int mt = blockIdx.x * 4 + wave;
    const int p = blockIdx.y;
    const long abase = ((long)mt * KI * 4) * 512 + lane * 8;
    const long wbase = ((long)p  * KI * 4) * 512 + lane * 8;

    floatx4 acc[4][4] = {};

    #pragma unroll
    for (int pass = 0; pass < (DUAL ? 2 : 1); ++pass) {
        const _Float16* A = pass ? A2f : A1f;
        const _Float16* W = pass ? W2f : W1f;
        #pragma unroll
        for (int k = 0; k < KI; ++k) {
            half8 af[4], bf[4];
            #pragma unroll
            for (int i = 0; i < 4; ++i)
                af[i] = *(const half8*)(A + abase + (k * 4 + i) * 512);
            #pragma unroll
            for (int j = 0; j < 4; ++j)
                bf[j] = *(const half8*)(W + wbase + (k * 4 + j) * 512);
            #pragma unroll
            for (int i = 0; i < 4; ++i)
                #pragma unroll
                for (int j = 0; j < 4; ++j)
                    acc[i][j] = __builtin_amdgcn_mfma_f32_16x16x32_f16(af[i], bf[j], acc[i][j], 0, 0, 0);
        }
    }

    // epilogue: C/D reg (i,j,r): m = mt*64+i*16+quad*4+r, n = p*64+j*16+lr
    const int n0 = p * 64;
    #pragma unroll
    for (int i = 0; i < 4; ++i) {
        #pragma unroll
        for (int j = 0; j < 4; ++j) {
            int nn = n0 + j * 16 + lr;
            float bn = bias[nn];
            long cbase = (((long)mt * KIO + (nn >> 5)) * 4 + i) * 512
                         + 16 * ((nn >> 3) & 3) * 8 + (nn & 7);
            #pragma unroll
            for (int r = 0; r < 4; ++r) {
                int lrm = quad * 4 + r;
                float v = acc[i][j][r] + bn;
                if (Cadd) {
                    int m = mt * 64 + i * 16 + lrm;
                    if (m > M - 1) m = M - 1;
                    v += Cadd[(long)m * N + nn];
                }
                if (relu) v = fmaxf(v, 0.f);
                Cf[cbase + lrm * 8] = (_Float16)v;
            }
        }
    }
}

// ---------------------------------------------------------------------------
// Classifier: dot64 over frag-linear h (KI=2). 16 threads/edge, 8-B loads.
// ---------------------------------------------------------------------------
__global__ void classify_kernel(const _Float16* __restrict__ hmi, const _Float16* __restrict__ hdi,
                                const int* __restrict__ ls, const int* __restrict__ ld,
                                float* __restrict__ out, int L) {
    long idx = (long)blockIdx.x * blockDim.x + threadIdx.x;
    int e = (int)(idx >> 4), t = (int)(idx & 15);
    if (e >= L) return;
    int c = t >> 1, h4 = (t & 1) * 4;       // chunk 0..7, half4 within chunk
    long coff = (((long)(c >> 2)) * 4) * 512 + 16 * (c & 3) * 8 + h4;
    int ra = ls[e], rb = ld[e];
    long offa = (((long)(ra >> 6) * 2) * 4 + ((ra >> 4) & 3)) * 512 + (ra & 15) * 8 + coff;
    long offb = (((long)(rb >> 6) * 2) * 4 + ((rb >> 4) & 3)) * 512 + (rb & 15) * 8 + coff;
    half4 a = *(const half4*)(hmi + offa);
    half4 b = *(const half4*)(hdi + offb);
    float s = (float)a.x * (float)b.x + (float)a.y * (float)b.y +
              (float)a.z * (float)b.z + (float)a.w * (float)b.w;
    #pragma unroll
    for (int off = 8; off >= 1; off >>= 1) s += __shfl_down(s, off, 16);
    if (t == 0) out[e] = s;
}

// ---------------------------------------------------------------------------
// Launch
// ---------------------------------------------------------------------------
extern "C" void kernel_launch(void* const* d_in, const int* in_sizes, int n_in,
                              void* d_out, int out_size, void* d_ws, size_t ws_size,
                              hipStream_t stream) {
    const float* x_mi   = (const float*)d_in[0];
    const float* x_di   = (const float*)d_in[1];
    const float* W_mi   = (const float*)d_in[2];
    const float* b_mi   = (const float*)d_in[3];
    const float* W_di   = (const float*)d_in[4];
    const float* b_di   = (const float*)d_in[5];
    const float* emb_mi = (const float*)d_in[6];
    const float* emb_di = (const float*)d_in[7];
    const float* Wl1_md = (const float*)d_in[8];
    const float* bl1_md = (const float*)d_in[9];
    const float* Wr1_md = (const float*)d_in[10];
    const float* Wl1_dm = (const float*)d_in[11];
    const float* bl1_dm = (const float*)d_in[12];
    const float* Wr1_dm = (const float*)d_in[13];
    const float* Wl2_md = (const float*)d_in[14];
    const float* bl2_md = (const float*)d_in[15];
    const float* Wr2_md = (const float*)d_in[16];
    const float* Wl2_dm = (const float*)d_in[17];
    const float* bl2_dm = (const float*)d_in[18];
    const float* Wr2_dm = (const float*)d_in[19];
    const float* Wl3_md = (const float*)d_in[20];
    const float* bl3_md = (const float*)d_in[21];
    const float* Wr3_md = (const float*)d_in[22];
    const float* Wl3_dm = (const float*)d_in[23];
    const float* bl3_dm = (const float*)d_in[24];
    const float* Wr3_dm = (const float*)d_in[25];
    const int* edge_src  = (const int*)d_in[26];
    const int* edge_dst  = (const int*)d_in[27];
    const int* label_src = (const int*)d_in[28];
    const int* label_dst = (const int*)d_in[29];
    const int E = in_sizes[26];
    const int L = in_sizes[28];
    float* out = (float*)d_out;

    // ---- workspace layout ----
    _Float16* hp = (_Float16*)d_ws;
    _Float16* wWmi  = hp; hp += 128 * 256;
    _Float16* wWdi  = hp; hp += 128 * 128;
    _Float16* wl1md = hp; hp += 256 * 128;
    _Float16* wr1md = hp; hp += 256 * 128;
    _Float16* wl1dm = hp; hp += 256 * 128;
    _Float16* wr1dm = hp; hp += 256 * 128;
    _Float16* wl2md = hp; hp += 128 * 256;
    _Float16* wr2md = hp; hp += 128 * 256;
    _Float16* wl2dm = hp; hp += 128 * 256;
    _Float16* wr2dm = hp; hp += 128 * 256;
    _Float16* wl3md = hp; hp += 64 * 128;
    _Float16* wr3md = hp; hp += 64 * 128;
    _Float16* wl3dm = hp; hp += 64 * 128;
    _Float16* wr3dm = hp; hp += 64 * 128;
    _Float16* xf_mi = hp; hp += (long)MI_P * 256;   // all frag-linear
    _Float16* xf_di = hp; hp += (long)DI_P * 128;
    _Float16* h_mi0 = hp; hp += (long)MI_P * 256;
    _Float16* h_mi1 = hp; hp += (long)MI_P * 256;
    _Float16* h_di0 = hp; hp += (long)DI_P * 256;
    _Float16* h_di1 = hp; hp += (long)DI_P * 256;
    _Float16* agghf = hp; hp += (long)MI_P * 256;

    int* ip = (int*)((((uintptr_t)hp) + 15) & ~(uintptr_t)15);
    int* deg_di = ip;  ip += N_DI;
    int* deg_mi = ip;  ip += N_MI;
    int* cur_di = ip;  ip += N_DI;
    int* cur_mi = ip;  ip += N_MI;
    int* row_di = ip;  ip += N_DI + 1;
    int* row_mi = ip;  ip += N_MI + 1;
    int* bs_di  = ip;  ip += 128;
    int* bs_mi  = ip;  ip += 128;
    int* csr_di = ip;  ip += E;
    int* csr_mi = ip;  ip += E;

    // ---- CSR build ----
    hipMemsetAsync(deg_di, 0, (size_t)(2 * (N_DI + N_MI)) * sizeof(int), stream);
    int eb = (E + 255) / 256;
    count_kernel<<<eb, 256, 0, stream>>>(edge_src, edge_dst, deg_mi, deg_di, E);
    scanA_kernel<<<dim3(MIB, 2), 256, 0, stream>>>(deg_di, deg_mi, bs_di, bs_mi);
    scanB_kernel<<<2, 64, 0, stream>>>(bs_di, bs_mi, row_di, row_mi);
    scanC_kernel<<<dim3(MIB, 2), 256, 0, stream>>>(deg_di, deg_mi, bs_di, bs_mi, row_di, row_mi);
    fill_kernel<<<eb, 256, 0, stream>>>(edge_src, edge_dst, row_mi, row_di,
                                        cur_mi, cur_di, csr_mi, csr_di, E);

    // ---- W converts -> frag-linear fp16 ----
    CvtW cw;
    const float* srcs[14] = {W_mi, W_di, Wl1_md, Wr1_md, Wl1_dm, Wr1_dm,
                             Wl2_md, Wr2_md, Wl2_dm, Wr2_dm, Wl3_md, Wr3_md, Wl3_dm, Wr3_dm};
    _Float16* dsts[14] = {wWmi, wWdi, wl1md, wr1md, wl1dm, wr1dm,
                          wl2md, wr2md, wl2dm, wr2dm, wl3md, wr3md, wl3dm, wr3dm};
    int Ks[14]  = {256, 128, 128, 128, 128, 128, 256, 256, 256, 256, 128, 128, 128, 128};
    int Ns[14]  = {128, 128, 256, 256, 256, 256, 128, 128, 128, 128, 64, 64, 64, 64};
    for (int i = 0; i < 14; ++i) {
        cw.s[i] = srcs[i]; cw.d[i] = dsts[i];
        cw.K[i] = Ks[i]; cw.KI[i] = Ks[i] / 32;
        cw.nch[i] = Ns[i] * Ks[i] / 8;
    }
    cvtw_kernel<<<dim3(16, 14), 256, 0, stream>>>(cw);

    // ---- x -> frag-linear fp16 ----
    cvt_frag<256><<<MI_P / 64, 256, 0, stream>>>(x_mi, xf_mi, N_MI);
    cvt_frag<128><<<DI_P / 64, 256, 0, stream>>>(x_di, xf_di, N_DI);

    // ---- init: h0 = x @ W^T + b + emb  (out 128 -> KIO=4) ----
    hgemm_f<8, 4, false><<<dim3(MI_P / 256, 2), 256, 0, stream>>>(
        xf_mi, wWmi, nullptr, nullptr, b_mi, emb_mi, h_mi0, N_MI, 128, 0);
    hgemm_f<4, 4, false><<<dim3(DI_P / 256, 2), 256, 0, stream>>>(
        xf_di, wWdi, nullptr, nullptr, b_di, emb_di, h_di0, N_DI, 128, 0);

    // ---- Layer 1: 128 -> 256, relu (KIO=8) ----
    agg2_kernel<128><<<(N_DI + 3) / 4, 256, 0, stream>>>(h_mi0, row_di, csr_di, agghf, N_DI);
    hgemm_f<4, 8, true><<<dim3(DI_P / 256, 4), 256, 0, stream>>>(
        agghf, wl1md, h_di0, wr1md, bl1_md, nullptr, h_di1, N_DI, 256, 1);
    agg2_kernel<128><<<(N_MI + 3) / 4, 256, 0, stream>>>(h_di0, row_mi, csr_mi, agghf, N_MI);
    hgemm_f<4, 8, true><<<dim3(MI_P / 256, 4), 256, 0, stream>>>(
        agghf, wl1dm, h_mi0, wr1dm, bl1_dm, nullptr, h_mi1, N_MI, 256, 1);

    // ---- Layer 2: 256 -> 128, relu (KIO=4) ----
    agg2_kernel<256><<<(N_DI + 3) / 4, 256, 0, stream>>>(h_mi1, row_di, csr_di, agghf, N_DI);
    hgemm_f<8, 4, true><<<dim3(DI_P / 256, 2), 256, 0, stream>>>(
        agghf, wl2md, h_di1, wr2md, bl2_md, nullptr, h_di0, N_DI, 128, 1);
    agg2_kernel<256><<<(N_MI + 3) / 4, 256, 0, stream>>>(h_di1, row_mi, csr_mi, agghf, N_MI);
    hgemm_f<8, 4, true><<<dim3(MI_P / 256, 2), 256, 0, stream>>>(
        agghf, wl2dm, h_mi1, wr2dm, bl2_dm, nullptr, h_mi0, N_MI, 128, 1);

    // ---- Layer 3: 128 -> 64, no relu (KIO=2) ----
    agg2_kernel<128><<<(N_DI + 3) / 4, 256, 0, stream>>>(h_mi0, row_di, csr_di, agghf, N_DI);
    hgemm_f<4, 2, true><<<dim3(DI_P / 256, 1), 256, 0, stream>>>(
        agghf, wl3md, h_di0, wr3md, bl3_md, nullptr, h_di1, N_DI, 64, 0);
    agg2_kernel<128><<<(N_MI + 3) / 4, 256, 0, stream>>>(h_di0, row_mi, csr_mi, agghf, N_MI);
    hgemm_f<4, 2, true><<<dim3(MI_P / 256, 1), 256, 0, stream>>>(
        agghf, wl3dm, h_mi0, wr3dm, bl3_dm, nullptr, h_mi1, N_MI, 64, 0);

    // ---- classifier ----
    classify_kernel<<<((long)L * 16 + 255) / 256, 256, 0, stream>>>(
        h_mi1, h_di1, label_src, label_dst, out, L);
}